// Round 1
// baseline (593.736 us; speedup 1.0000x reference)
//
#include <hip/hip_runtime.h>
#include <math.h>

#define BB 16
#define NP 8192
#define NV 42
#define NF 80
#define FEAT 256

// ---------------- Kernel A: optimize_cage ----------------
// One block per (b, cage vertex). Early-exit semantics: final c = initial c
// shrunk K times, K = first iteration index whose min-dist <= 0.4 (cap 100).
__global__ __launch_bounds__(256) void cage_opt_kernel(
    const float* __restrict__ tmpl,   // (1,3,42)
    const float* __restrict__ src,    // (B,3,N)
    float* __restrict__ cage)         // (B,3,42) scratch
{
  __shared__ float red[8];
  int b = blockIdx.x / NV;
  int v = blockIdx.x % NV;
  const float* sp = src + (size_t)b * 3 * NP;
  float cx = tmpl[v], cy = tmpl[NV + v], cz = tmpl[2 * NV + v];
  int k = 0;
  while (true) {
    float m = 3.4e38f;
    for (int i = threadIdx.x; i < NP; i += 256) {
      float dx = __fsub_rn(cx, sp[i]);
      float dy = __fsub_rn(cy, sp[NP + i]);
      float dz = __fsub_rn(cz, sp[2 * NP + i]);
      float ss = __fadd_rn(__fadd_rn(__fmul_rn(dx, dx), __fmul_rn(dy, dy)),
                           __fmul_rn(dz, dz));
      m = fminf(m, ss);
    }
    #pragma unroll
    for (int off = 32; off > 0; off >>= 1)
      m = fminf(m, __shfl_down(m, off, 64));
    int wid = threadIdx.x >> 6;
    __syncthreads();
    if ((threadIdx.x & 63) == 0) red[wid] = m;
    __syncthreads();
    if (threadIdx.x == 0) {
      float mm = fminf(fminf(red[0], red[1]), fminf(red[2], red[3]));
      red[4] = sqrtf(mm);   // sqrt(min) == min(sqrt): monotone
    }
    __syncthreads();
    float mind = red[4];
    if (mind > 0.4f && k < 100) {
      // exact replication of c + 0.01f*(-c), separate roundings, no fma
      cx = __fsub_rn(cx, __fmul_rn(0.01f, cx));
      cy = __fsub_rn(cy, __fmul_rn(0.01f, cy));
      cz = __fsub_rn(cz, __fmul_rn(0.01f, cz));
      k++;
    } else {
      break;
    }
  }
  if (threadIdx.x == 0) {
    cage[(size_t)b * 3 * NV + v]            = cx;
    cage[(size_t)b * 3 * NV + NV + v]       = cy;
    cage[(size_t)b * 3 * NV + 2 * NV + v]   = cz;
  }
}

// ---------------- MLP ----------------
__global__ void concat_kernel(const float* __restrict__ a,
                              const float* __restrict__ b,
                              float* __restrict__ out) {
  int i = blockIdx.x * 256 + threadIdx.x;   // B*512
  if (i >= BB * 2 * FEAT) return;
  int bb = i / (2 * FEAT), j = i % (2 * FEAT);
  out[i] = (j < FEAT) ? a[bb * FEAT + j] : b[bb * FEAT + j - FEAT];
}

__global__ void linear_kernel(const float* __restrict__ in,
                              const float* __restrict__ W,
                              const float* __restrict__ bias,
                              float* __restrict__ out,
                              int FI, int FO, int relu) {
  int o = blockIdx.x * 256 + threadIdx.x;
  int bb = blockIdx.y;
  if (o >= FO) return;
  float acc = bias[o];
  const float* inp = in + (size_t)bb * FI;
  for (int i = 0; i < FI; i++) acc = fmaf(inp[i], W[(size_t)i * FO + o], acc);
  if (relu) acc = fmaxf(acc, 0.f);
  out[(size_t)bb * FO + o] = acc;
}

// ---------------- Kernel C: finalize cage ----------------
__global__ void cage_finalize_kernel(const float* __restrict__ cage,   // (B,3,42)
                                     const float* __restrict__ ioff,   // (B,126)
                                     float* __restrict__ cage_t,       // (B,42,3)
                                     float* __restrict__ ncage_t) {    // (B,42,3)
  int i = blockIdx.x * 256 + threadIdx.x;
  if (i >= BB * 3 * NV) return;
  int bb = i / (3 * NV), r = i % (3 * NV);
  int d = r / NV, v = r % NV;
  float c  = cage[i];
  float nc = c + ioff[i];   // offset.reshape(B,3,42) has identical flat layout
  cage_t[(size_t)bb * NV * 3 + v * 3 + d]  = c;
  ncage_t[(size_t)bb * NV * 3 + v * 3 + d] = nc;
}

// ---------------- Kernel D: MVC weights + deformed ----------------
__global__ __launch_bounds__(256) void mvc_kernel(
    const float* __restrict__ src,      // (B,3,N)
    const float* __restrict__ cage_t,   // (B,42,3)
    const float* __restrict__ ncage_t,  // (B,42,3)
    const int* __restrict__ faces,      // (80,3)
    float* __restrict__ out_def,        // (B,3,N)
    float* __restrict__ out_w)          // (B,N,42)
{
  __shared__ float vxs[NV], vys[NV], vzs[NV];
  __shared__ float nxs[NV], nys[NV], nzs[NV];
  __shared__ int fid[NF * 3];
  __shared__ float wj[NV][256];         // per-thread column: conflict-free

  const float PI_F = 3.14159265358979323846f;
  int tid = threadIdx.x;
  int b = blockIdx.x >> 5;
  int p = ((blockIdx.x & 31) << 8) | tid;

  if (tid < NV) {
    vxs[tid] = cage_t[(size_t)b * NV * 3 + tid * 3 + 0];
    vys[tid] = cage_t[(size_t)b * NV * 3 + tid * 3 + 1];
    vzs[tid] = cage_t[(size_t)b * NV * 3 + tid * 3 + 2];
    nxs[tid] = ncage_t[(size_t)b * NV * 3 + tid * 3 + 0];
    nys[tid] = ncage_t[(size_t)b * NV * 3 + tid * 3 + 1];
    nzs[tid] = ncage_t[(size_t)b * NV * 3 + tid * 3 + 2];
  }
  if (tid < NF * 3) fid[tid] = faces[tid];
  #pragma unroll
  for (int c = 0; c < NV; c++) wj[c][tid] = 0.f;
  __syncthreads();

  float qx = src[(size_t)b * 3 * NP + p];
  float qy = src[(size_t)b * 3 * NP + NP + p];
  float qz = src[(size_t)b * 3 * NP + 2 * NP + p];

  bool anyInside = false;
  unsigned long long closeMask = 0ull;

  for (int i = 0; i < NF; i++) {
    int f0 = fid[3 * i], f1 = fid[3 * i + 1], f2 = fid[3 * i + 2];
    float a0x = vxs[f0] - qx, a0y = vys[f0] - qy, a0z = vzs[f0] - qz;
    float a1x = vxs[f1] - qx, a1y = vys[f1] - qy, a1z = vzs[f1] - qz;
    float a2x = vxs[f2] - qx, a2y = vys[f2] - qy, a2z = vzs[f2] - qz;
    float d0 = sqrtf(a0x * a0x + a0y * a0y + a0z * a0z);
    float d1 = sqrtf(a1x * a1x + a1y * a1y + a1z * a1z);
    float d2 = sqrtf(a2x * a2x + a2y * a2y + a2z * a2z);
    if (d0 < 1e-8f) closeMask |= (1ull << f0);
    if (d1 < 1e-8f) closeMask |= (1ull << f1);
    if (d2 < 1e-8f) closeMask |= (1ull << f2);
    float i0 = 1.f / d0, i1 = 1.f / d1, i2 = 1.f / d2;
    float u0x = a0x * i0, u0y = a0y * i0, u0z = a0z * i0;
    float u1x = a1x * i1, u1y = a1y * i1, u1z = a1z * i1;
    float u2x = a2x * i2, u2y = a2y * i2, u2z = a2z * i2;
    float ex, ey, ez;
    ex = u1x - u2x; ey = u1y - u2y; ez = u1z - u2z;
    float l0 = sqrtf(ex * ex + ey * ey + ez * ez);
    ex = u2x - u0x; ey = u2y - u0y; ez = u2z - u0z;
    float l1 = sqrtf(ex * ex + ey * ey + ez * ez);
    ex = u0x - u1x; ey = u0y - u1y; ez = u0z - u1z;
    float l2 = sqrtf(ex * ex + ey * ey + ez * ez);
    if (l0 >= 2.f) l0 = l0 - (l0 - 1.99998f);
    if (l1 >= 2.f) l1 = l1 - (l1 - 1.99998f);
    if (l2 >= 2.f) l2 = l2 - (l2 - 1.99998f);
    float th0 = 2.f * asinf(0.5f * l0);
    float th1 = 2.f * asinf(0.5f * l1);
    float th2 = 2.f * asinf(0.5f * l2);
    float h = 0.5f * (th0 + th1 + th2);
    if (PI_F - h < 1e-4f) anyInside = true;
    float sh  = sinf(h);
    float st0 = sinf(th0), st1 = sinf(th1), st2 = sinf(th2);
    float c0 = (2.f * sh) * sinf(h - th0) / (st1 * st2) - 1.f;
    float c1 = (2.f * sh) * sinf(h - th1) / (st2 * st0) - 1.f;
    float c2 = (2.f * sh) * sinf(h - th2) / (st0 * st1) - 1.f;
    c0 = fminf(fmaxf(c0, -0.99999f), 0.99999f);
    c1 = fminf(fmaxf(c1, -0.99999f), 0.99999f);
    c2 = fminf(fmaxf(c2, -0.99999f), 0.99999f);
    float det = u0x * (u1y * u2z - u1z * u2y)
              - u0y * (u1x * u2z - u1z * u2x)
              + u0z * (u1x * u2y - u1y * u2x);
    float sg = (det > 0.f) ? 1.f : ((det < 0.f) ? -1.f : 0.f);
    float s0 = sg * sqrtf(1.f - c0 * c0);
    float s1 = sg * sqrtf(1.f - c1 * c1);
    float s2 = sg * sqrtf(1.f - c2 * c2);
    float w0 = ((th0 - c1 * th2) - c2 * th1) / ((d0 * st1) * s2);
    float w1 = ((th1 - c2 * th0) - c0 * th2) / ((d1 * st2) * s0);
    float w2 = ((th2 - c0 * th1) - c1 * th0) / ((d2 * st0) * s1);
    wj[f0][tid] += w0;
    wj[f1][tid] += w1;
    wj[f2][tid] += w2;
  }

  if (anyInside) {   // rare path: exact `where(inside, ...)` semantics
    #pragma unroll
    for (int c = 0; c < NV; c++) wj[c][tid] = 0.f;
    for (int i = 0; i < NF; i++) {
      int f0 = fid[3 * i], f1 = fid[3 * i + 1], f2 = fid[3 * i + 2];
      float a0x = vxs[f0] - qx, a0y = vys[f0] - qy, a0z = vzs[f0] - qz;
      float a1x = vxs[f1] - qx, a1y = vys[f1] - qy, a1z = vzs[f1] - qz;
      float a2x = vxs[f2] - qx, a2y = vys[f2] - qy, a2z = vzs[f2] - qz;
      float d0 = sqrtf(a0x * a0x + a0y * a0y + a0z * a0z);
      float d1 = sqrtf(a1x * a1x + a1y * a1y + a1z * a1z);
      float d2 = sqrtf(a2x * a2x + a2y * a2y + a2z * a2z);
      float i0 = 1.f / d0, i1 = 1.f / d1, i2 = 1.f / d2;
      float u0x = a0x * i0, u0y = a0y * i0, u0z = a0z * i0;
      float u1x = a1x * i1, u1y = a1y * i1, u1z = a1z * i1;
      float u2x = a2x * i2, u2y = a2y * i2, u2z = a2z * i2;
      float ex, ey, ez;
      ex = u1x - u2x; ey = u1y - u2y; ez = u1z - u2z;
      float l0 = sqrtf(ex * ex + ey * ey + ez * ez);
      ex = u2x - u0x; ey = u2y - u0y; ez = u2z - u0z;
      float l1 = sqrtf(ex * ex + ey * ey + ez * ez);
      ex = u0x - u1x; ey = u0y - u1y; ez = u0z - u1z;
      float l2 = sqrtf(ex * ex + ey * ey + ez * ez);
      if (l0 >= 2.f) l0 = l0 - (l0 - 1.99998f);
      if (l1 >= 2.f) l1 = l1 - (l1 - 1.99998f);
      if (l2 >= 2.f) l2 = l2 - (l2 - 1.99998f);
      float th0 = 2.f * asinf(0.5f * l0);
      float th1 = 2.f * asinf(0.5f * l1);
      float th2 = 2.f * asinf(0.5f * l2);
      float h = 0.5f * (th0 + th1 + th2);
      if (PI_F - h < 1e-4f) {
        wj[f0][tid] += (sinf(th0) * d2) * d1;
        wj[f1][tid] += (sinf(th1) * d0) * d2;
        wj[f2][tid] += (sinf(th2) * d1) * d0;
      }
    }
  }

  if (closeMask) {   // rare path: query coincides with a cage vertex
    #pragma unroll
    for (int c = 0; c < NV; c++)
      wj[c][tid] = ((closeMask >> c) & 1ull) ? 1.f : 0.f;
  }

  float sum = 0.f;
  #pragma unroll
  for (int c = 0; c < NV; c++) sum += wj[c][tid];
  if (sum == 0.f) sum = 1.f;

  float ax = 0.f, ay = 0.f, az = 0.f;
  float* wrow = out_w + ((size_t)b * NP + p) * NV;
  #pragma unroll
  for (int c = 0; c < NV; c++) {
    float w = wj[c][tid] / sum;
    wrow[c] = w;
    ax += w * nxs[c];
    ay += w * nys[c];
    az += w * nzs[c];
  }
  out_def[(size_t)b * 3 * NP + p]            = ax;
  out_def[(size_t)b * 3 * NP + NP + p]       = ay;
  out_def[(size_t)b * 3 * NP + 2 * NP + p]   = az;
}

extern "C" void kernel_launch(void* const* d_in, const int* in_sizes, int n_in,
                              void* d_out, int out_size, void* d_ws, size_t ws_size,
                              hipStream_t stream) {
  (void)in_sizes; (void)n_in; (void)out_size; (void)d_ws; (void)ws_size;
  const float* src   = (const float*)d_in[0];
  // d_in[1] = target_shape: unused by the reference
  const float* sf    = (const float*)d_in[2];
  const float* tf    = (const float*)d_in[3];
  const float* tmpl  = (const float*)d_in[4];
  const int*   faces = (const int*)d_in[5];
  const float* W1 = (const float*)d_in[6];  const float* b1 = (const float*)d_in[7];
  const float* W2 = (const float*)d_in[8];  const float* b2 = (const float*)d_in[9];
  const float* W3 = (const float*)d_in[10]; const float* b3 = (const float*)d_in[11];
  const float* W4 = (const float*)d_in[12]; const float* b4 = (const float*)d_in[13];

  float* out = (float*)d_out;
  float* out_cage_t  = out;                 // (16,42,3)   2016
  float* out_ncage_t = out + 2016;          // (16,42,3)   2016
  float* out_def     = out + 4032;          // (16,3,8192) 393216
  float* out_w       = out + 397248;        // (16,8192,42) 5505024
  float* out_io      = out + 5902272;       // (16,126)    2016

  // scratch carved out of the weights region (fully overwritten by mvc_kernel)
  float* s_cage = out_w;           // 2016
  float* s_feat = out_w + 2016;    // 8192
  float* s_h1   = out_w + 10208;   // 8192
  float* s_h2   = out_w + 18400;   // 8192
  float* s_h3   = out_w + 26592;   // 4096

  cage_opt_kernel<<<dim3(BB * NV), dim3(256), 0, stream>>>(tmpl, src, s_cage);
  concat_kernel<<<dim3((BB * 2 * FEAT + 255) / 256), dim3(256), 0, stream>>>(sf, tf, s_feat);
  linear_kernel<<<dim3(2, BB), dim3(256), 0, stream>>>(s_feat, W1, b1, s_h1, 512, 512, 1);
  linear_kernel<<<dim3(2, BB), dim3(256), 0, stream>>>(s_h1, W2, b2, s_h2, 512, 512, 1);
  linear_kernel<<<dim3(1, BB), dim3(256), 0, stream>>>(s_h2, W3, b3, s_h3, 512, 256, 1);
  linear_kernel<<<dim3(1, BB), dim3(256), 0, stream>>>(s_h3, W4, b4, out_io, 256, 126, 0);
  cage_finalize_kernel<<<dim3((BB * 3 * NV + 255) / 256), dim3(256), 0, stream>>>(
      s_cage, out_io, out_cage_t, out_ncage_t);
  mvc_kernel<<<dim3(BB * (NP / 256)), dim3(256), 0, stream>>>(
      src, out_cage_t, out_ncage_t, faces, out_def, out_w);
}

// Round 2
// 354.033 us; speedup vs baseline: 1.6771x; 1.6771x over previous
//
#include <hip/hip_runtime.h>
#include <math.h>

#define BB 16
#define NP 8192
#define NV 42
#define NF 80
#define FEAT 256
#define PPB 128          // points per block (mvc)
#define FH  40           // faces per half-thread
#define WJS (PPB + 1)    // padded LDS stride for wj

__device__ __forceinline__ float rcp_f(float x) { return __builtin_amdgcn_rcpf(x); }
__device__ __forceinline__ float rsq_f(float x) { return __builtin_amdgcn_rsqf(x); }

// ---------------- Kernel A: optimize_cage ----------------
__global__ __launch_bounds__(256) void cage_opt_kernel(
    const float* __restrict__ tmpl,   // (1,3,42)
    const float* __restrict__ src,    // (B,3,N)
    float* __restrict__ cage)         // (B,3,42) scratch
{
  __shared__ float red[8];
  int b = blockIdx.x / NV;
  int v = blockIdx.x % NV;
  const float* sp = src + (size_t)b * 3 * NP;
  float cx = tmpl[v], cy = tmpl[NV + v], cz = tmpl[2 * NV + v];
  int k = 0;
  while (true) {
    float m = 3.4e38f;
    for (int i = threadIdx.x; i < NP; i += 256) {
      float dx = __fsub_rn(cx, sp[i]);
      float dy = __fsub_rn(cy, sp[NP + i]);
      float dz = __fsub_rn(cz, sp[2 * NP + i]);
      float ss = __fadd_rn(__fadd_rn(__fmul_rn(dx, dx), __fmul_rn(dy, dy)),
                           __fmul_rn(dz, dz));
      m = fminf(m, ss);
    }
    #pragma unroll
    for (int off = 32; off > 0; off >>= 1)
      m = fminf(m, __shfl_down(m, off, 64));
    int wid = threadIdx.x >> 6;
    __syncthreads();
    if ((threadIdx.x & 63) == 0) red[wid] = m;
    __syncthreads();
    if (threadIdx.x == 0) {
      float mm = fminf(fminf(red[0], red[1]), fminf(red[2], red[3]));
      red[4] = sqrtf(mm);
    }
    __syncthreads();
    float mind = red[4];
    if (mind > 0.4f && k < 100) {
      cx = __fsub_rn(cx, __fmul_rn(0.01f, cx));
      cy = __fsub_rn(cy, __fmul_rn(0.01f, cy));
      cz = __fsub_rn(cz, __fmul_rn(0.01f, cz));
      k++;
    } else {
      break;
    }
  }
  if (threadIdx.x == 0) {
    cage[(size_t)b * 3 * NV + v]          = cx;
    cage[(size_t)b * 3 * NV + NV + v]     = cy;
    cage[(size_t)b * 3 * NV + 2 * NV + v] = cz;
  }
}

// ---------------- MLP: LDS-staged linear (optionally fused concat) -----------
__global__ __launch_bounds__(256) void linear_kernel(
    const float* __restrict__ in0, const float* __restrict__ in1,
    const float* __restrict__ W, const float* __restrict__ bias,
    float* __restrict__ out, int FI, int FO, int relu)
{
  __shared__ float sIn[512];
  int bb = blockIdx.x;
  int tid = threadIdx.x;
  for (int i = tid; i < FI; i += 256) {
    float v;
    if (in1) v = (i < FEAT) ? in0[(size_t)bb * FEAT + i]
                            : in1[(size_t)bb * FEAT + i - FEAT];
    else     v = in0[(size_t)bb * FI + i];
    sIn[i] = v;
  }
  __syncthreads();
  for (int o = tid; o < FO; o += 256) {
    float acc = bias[o];
    const float* wp = W + o;
    #pragma unroll 4
    for (int i = 0; i < FI; i++) acc = fmaf(sIn[i], wp[(size_t)i * FO], acc);
    out[(size_t)bb * FO + o] = relu ? fmaxf(acc, 0.f) : acc;
  }
}

// ---------------- Kernel C: finalize cage ----------------
__global__ void cage_finalize_kernel(const float* __restrict__ cage,   // (B,3,42)
                                     const float* __restrict__ ioff,   // (B,126)
                                     float* __restrict__ cage_t,       // (B,42,3)
                                     float* __restrict__ ncage_t) {    // (B,42,3)
  int i = blockIdx.x * 256 + threadIdx.x;
  if (i >= BB * 3 * NV) return;
  int bb = i / (3 * NV), r = i % (3 * NV);
  int d = r / NV, v = r % NV;
  float c  = cage[i];
  float nc = c + ioff[i];
  cage_t[(size_t)bb * NV * 3 + v * 3 + d]  = c;
  ncage_t[(size_t)bb * NV * 3 + v * 3 + d] = nc;
}

// ---------------- Kernel D: MVC weights + deformed ----------------
// 256 threads: threads [0,128) do faces [0,40) of point p=tid,
//              threads [128,256) do faces [40,80) of point p=tid-128.
__global__ __launch_bounds__(256, 3) void mvc_kernel(
    const float* __restrict__ src,      // (B,3,N)
    const float* __restrict__ cage_t,   // (B,42,3)
    const float* __restrict__ ncage_t,  // (B,42,3)
    const int* __restrict__ faces,      // (80,3)
    float* __restrict__ out_def,        // (B,3,N)
    float* __restrict__ out_w)          // (B,N,42)
{
  __shared__ float vxs[NV], vys[NV], vzs[NV];
  __shared__ float nxs[NV], nys[NV], nzs[NV];
  __shared__ int fid[NF * 3];
  __shared__ float wj[2 * NV][WJS];
  __shared__ unsigned long long closeM[2][PPB];
  __shared__ int insideF[2][PPB];

  const float PI_F = 3.14159265358979323846f;
  int tid = threadIdx.x;
  int p   = tid & (PPB - 1);
  int hf  = tid >> 7;                      // face half
  int b    = blockIdx.x / (NP / PPB);
  int pblk = blockIdx.x % (NP / PPB);
  int gp   = pblk * PPB + p;

  if (tid < NV) {
    vxs[tid] = cage_t[(size_t)b * NV * 3 + tid * 3 + 0];
    vys[tid] = cage_t[(size_t)b * NV * 3 + tid * 3 + 1];
    vzs[tid] = cage_t[(size_t)b * NV * 3 + tid * 3 + 2];
    nxs[tid] = ncage_t[(size_t)b * NV * 3 + tid * 3 + 0];
    nys[tid] = ncage_t[(size_t)b * NV * 3 + tid * 3 + 1];
    nzs[tid] = ncage_t[(size_t)b * NV * 3 + tid * 3 + 2];
  }
  if (tid < NF * 3) fid[tid] = faces[tid];
  #pragma unroll
  for (int c = 0; c < NV; c++) wj[hf * NV + c][p] = 0.f;
  __syncthreads();

  float qx = src[(size_t)b * 3 * NP + gp];
  float qy = src[(size_t)b * 3 * NP + NP + gp];
  float qz = src[(size_t)b * 3 * NP + 2 * NP + gp];

  int anyInside = 0;
  unsigned long long closeMask = 0ull;

  // per-face geometry shared by main pass and inside re-pass
  auto face_geom = [&](int i, float& d0, float& d1, float& d2,
                       float& th0, float& th1, float& th2,
                       float& st0, float& st1, float& st2,
                       float& hh, float& sh, float& sm0, float& sm1, float& sm2,
                       float& sg) {
    int f0 = fid[3 * i], f1 = fid[3 * i + 1], f2 = fid[3 * i + 2];
    float a0x = vxs[f0] - qx, a0y = vys[f0] - qy, a0z = vzs[f0] - qz;
    float a1x = vxs[f1] - qx, a1y = vys[f1] - qy, a1z = vzs[f1] - qz;
    float a2x = vxs[f2] - qx, a2y = vys[f2] - qy, a2z = vzs[f2] - qz;
    float ss0 = a0x * a0x + a0y * a0y + a0z * a0z;
    float ss1 = a1x * a1x + a1y * a1y + a1z * a1z;
    float ss2 = a2x * a2x + a2y * a2y + a2z * a2z;
    float i0 = rsq_f(ss0), i1 = rsq_f(ss1), i2 = rsq_f(ss2);
    d0 = ss0 * i0; d1 = ss1 * i1; d2 = ss2 * i2;
    if (d0 < 1e-8f) closeMask |= (1ull << f0);
    if (d1 < 1e-8f) closeMask |= (1ull << f1);
    if (d2 < 1e-8f) closeMask |= (1ull << f2);
    float u0x = a0x * i0, u0y = a0y * i0, u0z = a0z * i0;
    float u1x = a1x * i1, u1y = a1y * i1, u1z = a1z * i1;
    float u2x = a2x * i2, u2y = a2y * i2, u2z = a2z * i2;
    float ex, ey, ez;
    ex = u1x - u2x; ey = u1y - u2y; ez = u1z - u2z;
    float x0 = 0.5f * sqrtf(ex * ex + ey * ey + ez * ez);
    ex = u2x - u0x; ey = u2y - u0y; ez = u2z - u0z;
    float x1 = 0.5f * sqrtf(ex * ex + ey * ey + ez * ez);
    ex = u0x - u1x; ey = u0y - u1y; ez = u0z - u1z;
    float x2 = 0.5f * sqrtf(ex * ex + ey * ey + ez * ez);
    // reference clamp: l>=2 -> l=1.99998  <=>  x>=1 -> x=0.99999
    if (x0 >= 1.f) x0 = 0.99999f;
    if (x1 >= 1.f) x1 = 0.99999f;
    if (x2 >= 1.f) x2 = 0.99999f;
    float cx0 = sqrtf(fmaxf(0.f, (1.f - x0) * (1.f + x0)));
    float cx1 = sqrtf(fmaxf(0.f, (1.f - x1) * (1.f + x1)));
    float cx2 = sqrtf(fmaxf(0.f, (1.f - x2) * (1.f + x2)));
    th0 = 2.f * asinf(x0);
    th1 = 2.f * asinf(x1);
    th2 = 2.f * asinf(x2);
    hh  = 0.5f * ((th0 + th1) + th2);
    st0 = 2.f * x0 * cx0;                  // sin(theta_i), algebraic
    st1 = 2.f * x1 * cx1;
    st2 = 2.f * x2 * cx2;
    float A1 = x0 * cx1 * cx2;
    float A2 = cx0 * x1 * cx2;
    float A3 = cx0 * cx1 * x2;
    float A4 = x0 * x1 * x2;
    sh  = ((A1 + A2) + A3) - A4;           // sin(h)
    sm0 = ((-A1 + A2) + A3) + A4;          // sin(h - th0)
    sm1 = ((A1 - A2) + A3) + A4;           // sin(h - th1)
    sm2 = ((A1 + A2) - A3) + A4;           // sin(h - th2)
    float det = u0x * (u1y * u2z - u1z * u2y)
              - u0y * (u1x * u2z - u1z * u2x)
              + u0z * (u1x * u2y - u1y * u2x);
    sg = (det > 0.f) ? 1.f : ((det < 0.f) ? -1.f : 0.f);
  };

  #pragma unroll 1
  for (int i = hf * FH; i < hf * FH + FH; i++) {
    float d0, d1, d2, th0, th1, th2, st0, st1, st2, hh, sh, sm0, sm1, sm2, sg;
    face_geom(i, d0, d1, d2, th0, th1, th2, st0, st1, st2,
              hh, sh, sm0, sm1, sm2, sg);
    if (PI_F - hh < 1e-4f) anyInside = 1;
    float twosh = 2.f * sh;
    float c0 = twosh * sm0 * rcp_f(st1 * st2) - 1.f;
    float c1 = twosh * sm1 * rcp_f(st2 * st0) - 1.f;
    float c2 = twosh * sm2 * rcp_f(st0 * st1) - 1.f;
    c0 = fminf(fmaxf(c0, -0.99999f), 0.99999f);
    c1 = fminf(fmaxf(c1, -0.99999f), 0.99999f);
    c2 = fminf(fmaxf(c2, -0.99999f), 0.99999f);
    float s0 = sg * sqrtf(1.f - c0 * c0);
    float s1 = sg * sqrtf(1.f - c1 * c1);
    float s2 = sg * sqrtf(1.f - c2 * c2);
    float w0 = ((th0 - c1 * th2) - c2 * th1) * rcp_f((d0 * st1) * s2);
    float w1 = ((th1 - c2 * th0) - c0 * th2) * rcp_f((d1 * st2) * s0);
    float w2 = ((th2 - c0 * th1) - c1 * th0) * rcp_f((d2 * st0) * s1);
    int f0 = fid[3 * i], f1 = fid[3 * i + 1], f2 = fid[3 * i + 2];
    wj[hf * NV + f0][p] += w0;
    wj[hf * NV + f1][p] += w1;
    wj[hf * NV + f2][p] += w2;
  }

  closeM[hf][p]  = closeMask;
  insideF[hf][p] = anyInside;
  __syncthreads();

  int mIn = insideF[0][p] | insideF[1][p];
  unsigned long long mCl = closeM[0][p] | closeM[1][p];

  if (mIn) {   // rare: exact `where(inside, ...)` semantics
    #pragma unroll
    for (int c = 0; c < NV; c++) wj[hf * NV + c][p] = 0.f;
    #pragma unroll 1
    for (int i = hf * FH; i < hf * FH + FH; i++) {
      float d0, d1, d2, th0, th1, th2, st0, st1, st2, hh, sh, sm0, sm1, sm2, sg;
      face_geom(i, d0, d1, d2, th0, th1, th2, st0, st1, st2,
                hh, sh, sm0, sm1, sm2, sg);
      if (PI_F - hh < 1e-4f) {
        int f0 = fid[3 * i], f1 = fid[3 * i + 1], f2 = fid[3 * i + 2];
        wj[hf * NV + f0][p] += (st0 * d2) * d1;
        wj[hf * NV + f1][p] += (st1 * d0) * d2;
        wj[hf * NV + f2][p] += (st2 * d1) * d0;
      }
    }
  }
  __syncthreads();

  // per-point: merge halves, close-override, normalize, deform
  if (tid < PPB) {
    float sum = 0.f;
    #pragma unroll
    for (int c = 0; c < NV; c++) {
      float w = wj[c][p] + wj[NV + c][p];
      if (mCl) w = ((mCl >> c) & 1ull) ? 1.f : 0.f;
      wj[c][p] = w;
      sum += w;
    }
    if (sum == 0.f) sum = 1.f;
    float inv = rcp_f(sum);
    float ax = 0.f, ay = 0.f, az = 0.f;
    #pragma unroll
    for (int c = 0; c < NV; c++) {
      float w = wj[c][p] * inv;
      wj[c][p] = w;
      ax += w * nxs[c];
      ay += w * nys[c];
      az += w * nzs[c];
    }
    out_def[(size_t)b * 3 * NP + gp]          = ax;
    out_def[(size_t)b * 3 * NP + NP + gp]     = ay;
    out_def[(size_t)b * 3 * NP + 2 * NP + gp] = az;
  }
  __syncthreads();

  // coalesced weight write: (PPB x 42) contiguous floats
  float* wbase = out_w + ((size_t)b * NP + pblk * PPB) * NV;
  for (int idx = tid; idx < PPB * NV; idx += 256) {
    int pp = idx / NV;
    int c  = idx - pp * NV;
    wbase[idx] = wj[c][pp];
  }
}

extern "C" void kernel_launch(void* const* d_in, const int* in_sizes, int n_in,
                              void* d_out, int out_size, void* d_ws, size_t ws_size,
                              hipStream_t stream) {
  (void)in_sizes; (void)n_in; (void)out_size; (void)d_ws; (void)ws_size;
  const float* src   = (const float*)d_in[0];
  const float* sf    = (const float*)d_in[2];
  const float* tf    = (const float*)d_in[3];
  const float* tmpl  = (const float*)d_in[4];
  const int*   faces = (const int*)d_in[5];
  const float* W1 = (const float*)d_in[6];  const float* b1 = (const float*)d_in[7];
  const float* W2 = (const float*)d_in[8];  const float* b2 = (const float*)d_in[9];
  const float* W3 = (const float*)d_in[10]; const float* b3 = (const float*)d_in[11];
  const float* W4 = (const float*)d_in[12]; const float* b4 = (const float*)d_in[13];

  float* out = (float*)d_out;
  float* out_cage_t  = out;                 // (16,42,3)   2016
  float* out_ncage_t = out + 2016;          // (16,42,3)   2016
  float* out_def     = out + 4032;          // (16,3,8192) 393216
  float* out_w       = out + 397248;        // (16,8192,42) 5505024
  float* out_io      = out + 5902272;       // (16,126)    2016

  // scratch carved out of the weights region (fully overwritten by mvc_kernel)
  float* s_cage = out_w;           // 2016
  float* s_h1   = out_w + 2016;    // 8192
  float* s_h2   = out_w + 10208;   // 8192
  float* s_h3   = out_w + 18400;   // 4096

  cage_opt_kernel<<<dim3(BB * NV), dim3(256), 0, stream>>>(tmpl, src, s_cage);
  linear_kernel<<<dim3(BB), dim3(256), 0, stream>>>(sf, tf, W1, b1, s_h1, 512, 512, 1);
  linear_kernel<<<dim3(BB), dim3(256), 0, stream>>>(s_h1, nullptr, W2, b2, s_h2, 512, 512, 1);
  linear_kernel<<<dim3(BB), dim3(256), 0, stream>>>(s_h2, nullptr, W3, b3, s_h3, 512, 256, 1);
  linear_kernel<<<dim3(BB), dim3(256), 0, stream>>>(s_h3, nullptr, W4, b4, out_io, 256, 126, 0);
  cage_finalize_kernel<<<dim3((BB * 3 * NV + 255) / 256), dim3(256), 0, stream>>>(
      s_cage, out_io, out_cage_t, out_ncage_t);
  mvc_kernel<<<dim3(BB * (NP / PPB)), dim3(256), 0, stream>>>(
      src, out_cage_t, out_ncage_t, faces, out_def, out_w);
}

// Round 3
// 168.755 us; speedup vs baseline: 3.5183x; 2.0979x over previous
//
#include <hip/hip_runtime.h>
#include <math.h>

#define BB 16
#define NP 8192
#define NV 42
#define NF 80
#define FEAT 256
#define PPB 64           // points per block (mvc)
#define FH  40           // faces per half-wave

__device__ __forceinline__ float rcp_f(float x)  { return __builtin_amdgcn_rcpf(x); }
__device__ __forceinline__ float rsq_f(float x)  { return __builtin_amdgcn_rsqf(x); }
__device__ __forceinline__ float sqrt_f(float x) { return __builtin_amdgcn_sqrtf(x); }

// theta = 2*asin(x), x in [0,1). Branchless minimax-ish (Taylor z<=0.25), |err|~1e-5.
__device__ __forceinline__ float theta_from_x(float x) {
  bool big = x > 0.5f;
  float z = big ? fmaf(-0.5f, x, 0.5f) : x * x;   // (1-x)/2 or x^2
  float s = big ? sqrt_f(z) : x;
  float P = fmaf(z, 0.022371875f, 0.030381944f);
  P = fmaf(z, P, 0.044642857f);
  P = fmaf(z, P, 0.075f);
  P = fmaf(z, P, 0.16666667f);
  float r = fmaf(s * z, P, s);                    // asin(s)
  return big ? fmaf(-4.f, r, 3.14159265358979f) : 2.f * r;
}

// ---------------- Kernel A: optimize_cage ----------------
__global__ __launch_bounds__(256) void cage_opt_kernel(
    const float* __restrict__ tmpl,   // (1,3,42)
    const float* __restrict__ src,    // (B,3,N)
    float* __restrict__ cage)         // (B,3,42) scratch
{
  __shared__ float red[8];
  int b = blockIdx.x / NV;
  int v = blockIdx.x % NV;
  const float* sp = src + (size_t)b * 3 * NP;
  float cx = tmpl[v], cy = tmpl[NV + v], cz = tmpl[2 * NV + v];
  int k = 0;
  while (true) {
    float m = 3.4e38f;
    for (int i = threadIdx.x; i < NP; i += 256) {
      float dx = __fsub_rn(cx, sp[i]);
      float dy = __fsub_rn(cy, sp[NP + i]);
      float dz = __fsub_rn(cz, sp[2 * NP + i]);
      float ss = __fadd_rn(__fadd_rn(__fmul_rn(dx, dx), __fmul_rn(dy, dy)),
                           __fmul_rn(dz, dz));
      m = fminf(m, ss);
    }
    #pragma unroll
    for (int off = 32; off > 0; off >>= 1)
      m = fminf(m, __shfl_down(m, off, 64));
    int wid = threadIdx.x >> 6;
    __syncthreads();
    if ((threadIdx.x & 63) == 0) red[wid] = m;
    __syncthreads();
    if (threadIdx.x == 0) {
      float mm = fminf(fminf(red[0], red[1]), fminf(red[2], red[3]));
      red[4] = sqrtf(mm);
    }
    __syncthreads();
    float mind = red[4];
    if (mind > 0.4f && k < 100) {
      cx = __fsub_rn(cx, __fmul_rn(0.01f, cx));
      cy = __fsub_rn(cy, __fmul_rn(0.01f, cy));
      cz = __fsub_rn(cz, __fmul_rn(0.01f, cz));
      k++;
    } else {
      break;
    }
  }
  if (threadIdx.x == 0) {
    cage[(size_t)b * 3 * NV + v]          = cx;
    cage[(size_t)b * 3 * NV + NV + v]     = cy;
    cage[(size_t)b * 3 * NV + 2 * NV + v] = cz;
  }
}

// ---------------- MLP: split-K linear, grid (FO/64, B), 256 thr ----------------
__global__ __launch_bounds__(256) void linear_splitk(
    const float* __restrict__ in0, const float* __restrict__ in1,
    const float* __restrict__ W, const float* __restrict__ bias,
    float* __restrict__ out, int FI, int FO, int relu)
{
  __shared__ float sIn[512];
  __shared__ float part[4][64];
  int bb = blockIdx.y;
  int tid = threadIdx.x;
  for (int i = tid; i < FI; i += 256) {
    float v;
    if (in1) v = (i < FEAT) ? in0[(size_t)bb * FEAT + i]
                            : in1[(size_t)bb * FEAT + i - FEAT];
    else     v = in0[(size_t)bb * FI + i];
    sIn[i] = v;
  }
  __syncthreads();
  int o = blockIdx.x * 64 + (tid & 63);
  int kk = tid >> 6;               // wave-uniform k chunk
  int seg = FI >> 2;
  float acc = 0.f;
  const float* wp = W + o;
  #pragma unroll 4
  for (int i = kk * seg; i < (kk + 1) * seg; i++)
    acc = fmaf(sIn[i], wp[(size_t)i * FO], acc);
  part[kk][tid & 63] = acc;
  __syncthreads();
  if (tid < 64) {
    float r = ((part[0][tid] + part[1][tid]) + (part[2][tid] + part[3][tid]))
              + bias[o];
    out[(size_t)bb * FO + o] = relu ? fmaxf(r, 0.f) : r;
  }
}

// ---------------- L4 + cage finalize (grid B, 128 thr) ----------------
__global__ __launch_bounds__(128) void l4_finalize_kernel(
    const float* __restrict__ h3,     // (B,256)
    const float* __restrict__ W4, const float* __restrict__ b4,
    const float* __restrict__ cage,   // (B,3,42) scratch
    float* __restrict__ out_io,       // (B,126)
    float* __restrict__ cage_t,       // (B,42,3)
    float* __restrict__ ncage_t)      // (B,42,3)
{
  __shared__ float sIn[256];
  int bb = blockIdx.x;
  int tid = threadIdx.x;
  sIn[tid] = h3[(size_t)bb * 256 + tid];
  sIn[tid + 128] = h3[(size_t)bb * 256 + tid + 128];
  __syncthreads();
  if (tid < 126) {
    float acc = b4[tid];
    const float* wp = W4 + tid;
    #pragma unroll 4
    for (int i = 0; i < 256; i++) acc = fmaf(sIn[i], wp[(size_t)i * 126], acc);
    out_io[(size_t)bb * 126 + tid] = acc;
    float c  = cage[(size_t)bb * 126 + tid];
    float nc = c + acc;
    int d = tid / NV, v = tid - d * NV;
    cage_t[(size_t)bb * NV * 3 + v * 3 + d]  = c;
    ncage_t[(size_t)bb * NV * 3 + v * 3 + d] = nc;
  }
}

// ---------------- Kernel D: MVC weights + deformed ----------------
// 128 threads: wave0 = faces [0,40) of point p=lane, wave1 = faces [40,80).
__global__ __launch_bounds__(128, 3) void mvc_kernel(
    const float* __restrict__ src,      // (B,3,N)
    const float* __restrict__ cage_t,   // (B,42,3)
    const float* __restrict__ ncage_t,  // (B,42,3)
    const int* __restrict__ faces,      // (80,3)
    float* __restrict__ out_def,        // (B,3,N)
    float* __restrict__ out_w)          // (B,N,42)
{
  __shared__ float4 vpos[NV];
  __shared__ float4 npos[NV];
  __shared__ int fidp[NF];
  __shared__ float wj[2 * NV][PPB];
  __shared__ unsigned long long closeM[2][PPB];
  __shared__ int insideF[2][PPB];

  const float PI_F = 3.14159265358979323846f;
  int tid = threadIdx.x;
  int p   = tid & (PPB - 1);
  int hf  = tid >> 6;
  int b    = blockIdx.x / (NP / PPB);
  int pblk = blockIdx.x % (NP / PPB);
  int gp   = pblk * PPB + p;

  if (tid < NV) {
    const float* cp = cage_t + (size_t)b * NV * 3 + tid * 3;
    vpos[tid] = make_float4(cp[0], cp[1], cp[2], 0.f);
    const float* np_ = ncage_t + (size_t)b * NV * 3 + tid * 3;
    npos[tid] = make_float4(np_[0], np_[1], np_[2], 0.f);
  }
  if (tid < NF) {
    int f0 = faces[3 * tid], f1 = faces[3 * tid + 1], f2 = faces[3 * tid + 2];
    fidp[tid] = f0 | (f1 << 6) | (f2 << 12);
  }
  #pragma unroll
  for (int c = 0; c < NV; c++) wj[hf * NV + c][p] = 0.f;
  __syncthreads();

  float qx = src[(size_t)b * 3 * NP + gp];
  float qy = src[(size_t)b * 3 * NP + NP + gp];
  float qz = src[(size_t)b * 3 * NP + 2 * NP + gp];

  int anyInside = 0;
  unsigned long long closeMask = 0ull;

  auto face_geom = [&](int i, int& f0, int& f1, int& f2,
                       float& d0, float& d1, float& d2,
                       float& th0, float& th1, float& th2,
                       float& st0, float& st1, float& st2,
                       float& hh, float& sh, float& sm0, float& sm1, float& sm2,
                       float& sg) {
    int pk = fidp[i];
    f0 = pk & 63; f1 = (pk >> 6) & 63; f2 = pk >> 12;
    float4 v0 = vpos[f0], v1 = vpos[f1], v2 = vpos[f2];
    float a0x = v0.x - qx, a0y = v0.y - qy, a0z = v0.z - qz;
    float a1x = v1.x - qx, a1y = v1.y - qy, a1z = v1.z - qz;
    float a2x = v2.x - qx, a2y = v2.y - qy, a2z = v2.z - qz;
    float ss0 = fmaf(a0x, a0x, fmaf(a0y, a0y, a0z * a0z));
    float ss1 = fmaf(a1x, a1x, fmaf(a1y, a1y, a1z * a1z));
    float ss2 = fmaf(a2x, a2x, fmaf(a2y, a2y, a2z * a2z));
    float i0 = rsq_f(ss0), i1 = rsq_f(ss1), i2 = rsq_f(ss2);
    d0 = ss0 * i0; d1 = ss1 * i1; d2 = ss2 * i2;
    if (d0 < 1e-8f) closeMask |= (1ull << f0);
    if (d1 < 1e-8f) closeMask |= (1ull << f1);
    if (d2 < 1e-8f) closeMask |= (1ull << f2);
    float u0x = a0x * i0, u0y = a0y * i0, u0z = a0z * i0;
    float u1x = a1x * i1, u1y = a1y * i1, u1z = a1z * i1;
    float u2x = a2x * i2, u2y = a2y * i2, u2z = a2z * i2;
    float ex, ey, ez;
    ex = u1x - u2x; ey = u1y - u2y; ez = u1z - u2z;
    float x0 = 0.5f * sqrt_f(fmaf(ex, ex, fmaf(ey, ey, ez * ez)));
    ex = u2x - u0x; ey = u2y - u0y; ez = u2z - u0z;
    float x1 = 0.5f * sqrt_f(fmaf(ex, ex, fmaf(ey, ey, ez * ez)));
    ex = u0x - u1x; ey = u0y - u1y; ez = u0z - u1z;
    float x2 = 0.5f * sqrt_f(fmaf(ex, ex, fmaf(ey, ey, ez * ez)));
    if (x0 >= 1.f) x0 = 0.99999f;
    if (x1 >= 1.f) x1 = 0.99999f;
    if (x2 >= 1.f) x2 = 0.99999f;
    float cx0 = sqrt_f(fmaxf(fmaf(-x0, x0, 1.f), 0.f));
    float cx1 = sqrt_f(fmaxf(fmaf(-x1, x1, 1.f), 0.f));
    float cx2 = sqrt_f(fmaxf(fmaf(-x2, x2, 1.f), 0.f));
    th0 = theta_from_x(x0);
    th1 = theta_from_x(x1);
    th2 = theta_from_x(x2);
    hh  = 0.5f * ((th0 + th1) + th2);
    st0 = 2.f * (x0 * cx0);
    st1 = 2.f * (x1 * cx1);
    st2 = 2.f * (x2 * cx2);
    float A1 = x0 * (cx1 * cx2);
    float A2 = x1 * (cx0 * cx2);
    float A3 = x2 * (cx0 * cx1);
    float A4 = x0 * (x1 * x2);
    sh  = ((A1 + A2) + A3) - A4;
    sm0 = ((-A1 + A2) + A3) + A4;
    sm1 = ((A1 - A2) + A3) + A4;
    sm2 = ((A1 + A2) - A3) + A4;
    float det = u0x * fmaf(u1y, u2z, -u1z * u2y)
              - u0y * fmaf(u1x, u2z, -u1z * u2x)
              + u0z * fmaf(u1x, u2y, -u1y * u2x);
    sg = (det > 0.f) ? 1.f : ((det < 0.f) ? -1.f : 0.f);
  };

  #pragma unroll 1
  for (int i = hf * FH; i < hf * FH + FH; i++) {
    int f0, f1, f2;
    float d0, d1, d2, th0, th1, th2, st0, st1, st2, hh, sh, sm0, sm1, sm2, sg;
    face_geom(i, f0, f1, f2, d0, d1, d2, th0, th1, th2, st0, st1, st2,
              hh, sh, sm0, sm1, sm2, sg);
    if (PI_F - hh < 1e-4f) anyInside = 1;
    float twosh = 2.f * sh;
    float c0 = fmaf(twosh * sm0, rcp_f(st1 * st2), -1.f);
    float c1 = fmaf(twosh * sm1, rcp_f(st2 * st0), -1.f);
    float c2 = fmaf(twosh * sm2, rcp_f(st0 * st1), -1.f);
    c0 = fminf(fmaxf(c0, -0.99999f), 0.99999f);
    c1 = fminf(fmaxf(c1, -0.99999f), 0.99999f);
    c2 = fminf(fmaxf(c2, -0.99999f), 0.99999f);
    float s0 = sg * sqrt_f(fmaf(-c0, c0, 1.f));
    float s1 = sg * sqrt_f(fmaf(-c1, c1, 1.f));
    float s2 = sg * sqrt_f(fmaf(-c2, c2, 1.f));
    float w0 = (fmaf(-c2, th1, fmaf(-c1, th2, th0))) * rcp_f((d0 * st1) * s2);
    float w1 = (fmaf(-c0, th2, fmaf(-c2, th0, th1))) * rcp_f((d1 * st2) * s0);
    float w2 = (fmaf(-c1, th0, fmaf(-c0, th1, th2))) * rcp_f((d2 * st0) * s1);
    wj[hf * NV + f0][p] += w0;
    wj[hf * NV + f1][p] += w1;
    wj[hf * NV + f2][p] += w2;
  }

  closeM[hf][p]  = closeMask;
  insideF[hf][p] = anyInside;
  __syncthreads();

  int mIn = insideF[0][p] | insideF[1][p];
  unsigned long long mCl = closeM[0][p] | closeM[1][p];

  if (mIn) {   // rare: exact `where(inside, ...)` semantics
    #pragma unroll
    for (int c = 0; c < NV; c++) wj[hf * NV + c][p] = 0.f;
    #pragma unroll 1
    for (int i = hf * FH; i < hf * FH + FH; i++) {
      int f0, f1, f2;
      float d0, d1, d2, th0, th1, th2, st0, st1, st2, hh, sh, sm0, sm1, sm2, sg;
      face_geom(i, f0, f1, f2, d0, d1, d2, th0, th1, th2, st0, st1, st2,
                hh, sh, sm0, sm1, sm2, sg);
      if (PI_F - hh < 1e-4f) {
        wj[hf * NV + f0][p] += (st0 * d2) * d1;
        wj[hf * NV + f1][p] += (st1 * d0) * d2;
        wj[hf * NV + f2][p] += (st2 * d1) * d0;
      }
    }
  }
  __syncthreads();

  if (tid < PPB) {
    float sum = 0.f;
    #pragma unroll
    for (int c = 0; c < NV; c++) {
      float w = wj[c][p] + wj[NV + c][p];
      if (mCl) w = ((mCl >> c) & 1ull) ? 1.f : 0.f;
      wj[c][p] = w;
      sum += w;
    }
    if (sum == 0.f) sum = 1.f;
    float inv = rcp_f(sum);
    float ax = 0.f, ay = 0.f, az = 0.f;
    #pragma unroll
    for (int c = 0; c < NV; c++) {
      float w = wj[c][p] * inv;
      wj[c][p] = w;
      float4 n = npos[c];
      ax = fmaf(w, n.x, ax);
      ay = fmaf(w, n.y, ay);
      az = fmaf(w, n.z, az);
    }
    out_def[(size_t)b * 3 * NP + gp]          = ax;
    out_def[(size_t)b * 3 * NP + NP + gp]     = ay;
    out_def[(size_t)b * 3 * NP + 2 * NP + gp] = az;
  }
  __syncthreads();

  // coalesced weight write: (PPB x 42) contiguous floats
  float* wbase = out_w + ((size_t)b * NP + pblk * PPB) * NV;
  for (int idx = tid; idx < PPB * NV; idx += 128) {
    int pp = idx / NV;
    int c  = idx - pp * NV;
    wbase[idx] = wj[c][pp];
  }
}

extern "C" void kernel_launch(void* const* d_in, const int* in_sizes, int n_in,
                              void* d_out, int out_size, void* d_ws, size_t ws_size,
                              hipStream_t stream) {
  (void)in_sizes; (void)n_in; (void)out_size; (void)d_ws; (void)ws_size;
  const float* src   = (const float*)d_in[0];
  const float* sf    = (const float*)d_in[2];
  const float* tf    = (const float*)d_in[3];
  const float* tmpl  = (const float*)d_in[4];
  const int*   faces = (const int*)d_in[5];
  const float* W1 = (const float*)d_in[6];  const float* b1 = (const float*)d_in[7];
  const float* W2 = (const float*)d_in[8];  const float* b2 = (const float*)d_in[9];
  const float* W3 = (const float*)d_in[10]; const float* b3 = (const float*)d_in[11];
  const float* W4 = (const float*)d_in[12]; const float* b4 = (const float*)d_in[13];

  float* out = (float*)d_out;
  float* out_cage_t  = out;                 // (16,42,3)   2016
  float* out_ncage_t = out + 2016;          // (16,42,3)   2016
  float* out_def     = out + 4032;          // (16,3,8192) 393216
  float* out_w       = out + 397248;        // (16,8192,42) 5505024
  float* out_io      = out + 5902272;       // (16,126)    2016

  // scratch carved out of the weights region (fully overwritten by mvc_kernel)
  float* s_cage = out_w;           // 2016
  float* s_h1   = out_w + 2016;    // 8192
  float* s_h2   = out_w + 10208;   // 8192
  float* s_h3   = out_w + 18400;   // 4096

  cage_opt_kernel<<<dim3(BB * NV), dim3(256), 0, stream>>>(tmpl, src, s_cage);
  linear_splitk<<<dim3(8, BB), dim3(256), 0, stream>>>(sf, tf, W1, b1, s_h1, 512, 512, 1);
  linear_splitk<<<dim3(8, BB), dim3(256), 0, stream>>>(s_h1, nullptr, W2, b2, s_h2, 512, 512, 1);
  linear_splitk<<<dim3(4, BB), dim3(256), 0, stream>>>(s_h2, nullptr, W3, b3, s_h3, 512, 256, 1);
  l4_finalize_kernel<<<dim3(BB), dim3(128), 0, stream>>>(
      s_h3, W4, b4, s_cage, out_io, out_cage_t, out_ncage_t);
  mvc_kernel<<<dim3(BB * (NP / PPB)), dim3(128), 0, stream>>>(
      src, out_cage_t, out_ncage_t, faces, out_def, out_w);
}